// Round 1
// baseline (357.573 us; speedup 1.0000x reference)
//
#include <hip/hip_runtime.h>
#include <hip/hip_bf16.h>
#include <cmath>

// ---------- reduction helpers (wave64) ----------
__device__ inline float waveReduceSum(float v) {
#pragma unroll
    for (int o = 32; o > 0; o >>= 1) v += __shfl_xor(v, o, 64);
    return v;
}
__device__ inline float waveReduceMax(float v) {
#pragma unroll
    for (int o = 32; o > 0; o >>= 1) v = fmaxf(v, __shfl_xor(v, o, 64));
    return v;
}
// valid result on thread 0 only; block size 256 (4 waves)
__device__ inline float blockReduceSum(float v, float* s) {
    int lane = threadIdx.x & 63, wv = threadIdx.x >> 6;
    v = waveReduceSum(v);
    if (lane == 0) s[wv] = v;
    __syncthreads();
    float r = 0.f;
    if (wv == 0) {
        r = (lane < 4) ? s[lane] : 0.f;
        r = waveReduceSum(r);
    }
    __syncthreads();
    return r;
}
__device__ inline float blockReduceMax(float v, float* s) {
    int lane = threadIdx.x & 63, wv = threadIdx.x >> 6;
    v = waveReduceMax(v);
    if (lane == 0) s[wv] = v;
    __syncthreads();
    float r = -3.4e38f;
    if (wv == 0) {
        r = (lane < 4) ? s[lane] : -3.4e38f;
        r = waveReduceMax(r);
    }
    __syncthreads();
    return r;
}

__device__ inline float logsig(float x) {
    // stable log(sigmoid(x)) = min(x,0) - log1p(exp(-|x|))
    return fminf(x, 0.f) - log1pf(expf(-fabsf(x)));
}

#define H 256
#define W 256
#define NIMG 64
#define HW 65536

// ---------- kernel A: pairwise loss partials + row maxes ----------
__global__ __launch_bounds__(256) void k_pairwise(
    const float* __restrict__ src, const float* __restrict__ ts,
    const int* __restrict__ bm,
    float* __restrict__ part_st, float* __restrict__ part_t,
    float* __restrict__ rowmax_x, float* __restrict__ rowmax_b)
{
    __shared__ float s_lfg[3][W];
    __shared__ float s_x[3][W];
    __shared__ float red[4];
    const int h = blockIdx.x, n = blockIdx.y, w = threadIdx.x;
    const float* srcn = src + (size_t)n * HW;
#pragma unroll
    for (int r = 0; r < 3; r++) {
        int hr = h + (r - 1) * 2;
        float xv = 0.f, lf = 0.f;
        if (hr >= 0 && hr < H) { xv = srcn[hr * W + w]; lf = logsig(xv); }
        s_x[r][w] = xv; s_lfg[r][w] = lf;
    }
    __syncthreads();
    const float xc = s_x[1][w];
    const float lfc = s_lfg[1][w];
    const float lbc = lfc - xc;             // log_sigmoid(-x) = log_sigmoid(x) - x
    const float bmf = (float)bm[(size_t)n * HW + h * W + w];
    const float* tsn = ts + (size_t)n * 8 * HW + h * W + w;

    const int DR[8] = {-2, -2, -2, 0, 0, 2, 2, 2};
    const int DC[8] = {-2, 0, 2, -2, 2, -2, 0, 2};
    float st = 0.f, tt = 0.f;
#pragma unroll
    for (int p = 0; p < 8; p++) {
        const int hr = h + DR[p];
        const int wc = w + DC[p];
        const bool valid = (hr >= 0) && (hr < H) && (wc >= 0) && (wc < W);
        const int r = (DR[p] + 2) >> 1;
        const int wcc = min(max(wc, 0), W - 1);
        const float lfn = valid ? s_lfg[r][wcc] : 0.f;  // zero-padded neighbor
        const float xn = valid ? s_x[r][wcc] : 0.f;
        const float a = lfc + lfn;
        const float b2 = lbc + (lfn - xn);
        const float m = fmaxf(a, b2);
        const float sim = -(m + log1pf(expf(-fabsf(a - b2))));
        const float tsv = tsn[(size_t)p * HW];
        const float tg = (tsv >= 0.3f) ? bmf : 0.f;
        st = fmaf(sim, tg, st);
        tt += tg;
    }
    const float sst = blockReduceSum(st, red);
    const float stt = blockReduceSum(tt, red);
    const float mx = blockReduceMax(xc, red);
    const float mb = blockReduceMax(bmf, red);
    if (threadIdx.x == 0) {
        const int o = n * H + h;
        part_st[o] = sst;
        part_t[o] = stt;
        rowmax_x[o] = mx;
        rowmax_b[o] = mb;
    }
}

// ---------- kernel B: column-max partials (32-row chunks) ----------
__global__ __launch_bounds__(256) void k_colmax(
    const float* __restrict__ src, const int* __restrict__ bm,
    float* __restrict__ colpart_x, float* __restrict__ colpart_b)
{
    const int chunk = blockIdx.x, n = blockIdx.y, w = threadIdx.x;
    const float* s = src + (size_t)n * HW + chunk * 32 * W + w;
    const int* b = bm + (size_t)n * HW + chunk * 32 * W + w;
    float mx = -3.4e38f, mb = 0.f;
#pragma unroll 8
    for (int r = 0; r < 32; r++) {
        mx = fmaxf(mx, s[r * W]);
        mb = fmaxf(mb, (float)b[r * W]);
    }
    const int o = (n * 8 + chunk) * W + w;
    colpart_x[o] = mx;
    colpart_b[o] = mb;
}

// ---------- kernel C: per-image projection loss ----------
__global__ __launch_bounds__(256) void k_proj(
    const float* __restrict__ colpart_x, const float* __restrict__ colpart_b,
    const float* __restrict__ rowmax_x, const float* __restrict__ rowmax_b,
    float* __restrict__ proj)
{
    __shared__ float red[4];
    const int n = blockIdx.x, t = threadIdx.x;
    float cx = -3.4e38f, cb = 0.f;
#pragma unroll
    for (int c = 0; c < 8; c++) {
        cx = fmaxf(cx, colpart_x[(n * 8 + c) * W + t]);
        cb = fmaxf(cb, colpart_b[(n * 8 + c) * W + t]);
    }
    const float iy = 1.f / (1.f + expf(-cx));
    const float ty = cb;
    const float rx = rowmax_x[n * H + t];
    const float ix = 1.f / (1.f + expf(-rx));
    const float tx = rowmax_b[n * H + t];

    const float Sxy = blockReduceSum(ix * tx, red);
    const float Sxx = blockReduceSum(ix * ix, red);
    const float Stx = blockReduceSum(tx * tx, red);
    const float Syw = blockReduceSum(iy * ty, red);
    const float Syy = blockReduceSum(iy * iy, red);
    const float Sty = blockReduceSum(ty * ty, red);
    if (t == 0) {
        const float eps = 0.001f;
        const float lx = 1.f - 2.f * Sxy / (Sxx + Stx + eps);
        const float ly = 1.f - 2.f * Syw / (Syy + Sty + eps);
        proj[n] = lx + ly;
    }
}

// ---------- kernel D: CE + final combine ----------
__global__ __launch_bounds__(256) void k_final(
    const float* __restrict__ logits, const int* __restrict__ tcls,
    const float* __restrict__ ew, const int* __restrict__ num_masks,
    const float* __restrict__ part_st, const float* __restrict__ part_t,
    const float* __restrict__ proj, float* __restrict__ out)
{
    __shared__ float red[4];
    const int t = threadIdx.x;
    float s1 = 0.f, s2 = 0.f;
    for (int i = t; i < NIMG * H; i += 256) { s1 += part_st[i]; s2 += part_t[i]; }
    const float sum_st = blockReduceSum(s1, red);
    const float sum_t = blockReduceSum(s2, red);
    const float pj = (t < NIMG) ? proj[t] : 0.f;
    const float sum_pj = blockReduceSum(pj, red);

    float wn = 0.f, wsum = 0.f;
    if (t < 200) {
        const float* row = logits + t * 81;
        float mx = -3.4e38f;
        for (int c = 0; c < 81; c++) mx = fmaxf(mx, row[c]);
        float se = 0.f;
        for (int c = 0; c < 81; c++) se += expf(row[c] - mx);
        const float lse = mx + logf(se);
        const int tc = tcls[t];
        const float nll = lse - row[tc];
        const float wv = ew[tc];
        wn = wv * nll;
        wsum = wv;
    }
    const float Swn = blockReduceSum(wn, red);
    const float Sw = blockReduceSum(wsum, red);
    if (t == 0) {
        const float nm = (float)max(num_masks[0], 1);
        const float loss_ce = Swn / Sw;
        const float loss_pw = sum_st / fmaxf(sum_t, 1.f) / nm;
        const float loss_pj = sum_pj / nm;
        out[0] = loss_ce + loss_pw + loss_pj;
    }
}

extern "C" void kernel_launch(void* const* d_in, const int* in_sizes, int n_in,
                              void* d_out, int out_size, void* d_ws, size_t ws_size,
                              hipStream_t stream) {
    const float* pred_logits = (const float*)d_in[0];  // [2,100,81]
    const float* src         = (const float*)d_in[1];  // [64,256,256]
    const float* ew          = (const float*)d_in[2];  // [81]
    const float* ts          = (const float*)d_in[3];  // [64,8,256,256]
    const int*   tcls        = (const int*)d_in[4];    // [2,100]
    const int*   bm          = (const int*)d_in[5];    // [64,256,256]
    const int*   nmasks      = (const int*)d_in[6];    // [1]
    float* out = (float*)d_out;

    float* ws = (float*)d_ws;
    float* part_st   = ws;            // 16384
    float* part_t    = ws + 16384;    // 16384
    float* rowmax_x  = ws + 32768;    // 16384
    float* rowmax_b  = ws + 49152;    // 16384
    float* colpart_x = ws + 65536;    // 64*8*256 = 131072
    float* colpart_b = ws + 196608;   // 131072
    float* proj      = ws + 327680;   // 64

    k_pairwise<<<dim3(H, NIMG), 256, 0, stream>>>(src, ts, bm, part_st, part_t, rowmax_x, rowmax_b);
    k_colmax<<<dim3(8, NIMG), 256, 0, stream>>>(src, bm, colpart_x, colpart_b);
    k_proj<<<NIMG, 256, 0, stream>>>(colpart_x, colpart_b, rowmax_x, rowmax_b, proj);
    k_final<<<1, 256, 0, stream>>>(pred_logits, tcls, ew, nmasks, part_st, part_t, proj, out);
}

// Round 2
// 274.267 us; speedup vs baseline: 1.3037x; 1.3037x over previous
//
#include <hip/hip_runtime.h>
#include <hip/hip_bf16.h>
#include <cmath>

// ---------- reduction helpers (wave64) ----------
__device__ inline float waveReduceSum(float v) {
#pragma unroll
    for (int o = 32; o > 0; o >>= 1) v += __shfl_xor(v, o, 64);
    return v;
}
__device__ inline float waveReduceMax(float v) {
#pragma unroll
    for (int o = 32; o > 0; o >>= 1) v = fmaxf(v, __shfl_xor(v, o, 64));
    return v;
}
// valid result on thread 0 only; block size 256 (4 waves)
__device__ inline float blockReduceSum(float v, float* s) {
    int lane = threadIdx.x & 63, wv = threadIdx.x >> 6;
    v = waveReduceSum(v);
    if (lane == 0) s[wv] = v;
    __syncthreads();
    float r = 0.f;
    if (wv == 0) {
        r = (lane < 4) ? s[lane] : 0.f;
        r = waveReduceSum(r);
    }
    __syncthreads();
    return r;
}
__device__ inline float blockReduceMax(float v, float* s) {
    int lane = threadIdx.x & 63, wv = threadIdx.x >> 6;
    v = waveReduceMax(v);
    if (lane == 0) s[wv] = v;
    __syncthreads();
    float r = -3.4e38f;
    if (wv == 0) {
        r = (lane < 4) ? s[lane] : -3.4e38f;
        r = waveReduceMax(r);
    }
    __syncthreads();
    return r;
}

#define H 256
#define W 256
#define NIMG 64
#define HW 65536
#define RG 16   // rows per block in k_pairwise

// ---------- kernel A: pairwise loss partials + row maxes (sigmoid-space) ----------
// sim = -log( sig_c*sig_n + (1-sig_c)*(1-sig_n) ); padded neighbor -> P=1 -> sim=0.
__global__ __launch_bounds__(256) void k_pairwise(
    const float* __restrict__ src, const float* __restrict__ ts,
    const int* __restrict__ bm,
    float* __restrict__ part_st, float* __restrict__ part_t,
    float* __restrict__ rowsig, float* __restrict__ rowmax_b)
{
    __shared__ float s_sig[RG + 4][W];
    __shared__ float red[4];
    const int hg = blockIdx.x, n = blockIdx.y, w = threadIdx.x;
    const int h0 = hg * RG;
    const float* srcn = src + (size_t)n * HW;
    // stage RG+4 rows of sigmoid(x)
#pragma unroll
    for (int r = 0; r < RG + 4; r++) {
        const int gr = h0 - 2 + r;
        float s = 0.5f;
        if (gr >= 0 && gr < H) {
            const float x = srcn[gr * W + w];
            s = __builtin_amdgcn_rcpf(1.f + __expf(-x));
        }
        s_sig[r][w] = s;
    }
    __syncthreads();
    const int* bmn = bm + (size_t)n * HW;
    const float* tsbase = ts + (size_t)n * 8 * HW + w;

    const int DR[8] = {-2, -2, -2, 0, 0, 2, 2, 2};
    const int DC[8] = {-2, 0, 2, -2, 2, -2, 0, 2};
    float st = 0.f, tt = 0.f;
    for (int rr = 0; rr < RG; rr++) {
        const int h = h0 + rr;
        const int ci = rr + 2;
        const float sc = s_sig[ci][w];
        const float omc = 1.f - sc;
        const float bmf = (float)bmn[h * W + w];
        const float* tsn = tsbase + h * W;
#pragma unroll
        for (int p = 0; p < 8; p++) {
            const int hr = h + DR[p];
            const int wc = w + DC[p];
            const bool valid = (hr >= 0) && (hr < H) && (wc >= 0) && (wc < W);
            const int wcc = min(max(wc, 0), W - 1);
            const float sn = s_sig[ci + DR[p]][wcc];
            const float P = valid ? fmaf(sc, sn, omc * (1.f - sn)) : 1.f;
            const float tsv = tsn[(size_t)p * HW];
            const float tg = (tsv >= 0.3f) ? bmf : 0.f;
            st = fmaf(-__logf(P), tg, st);
            tt += tg;
        }
        // per-row maxes (sigmoid-space for x: monotonic, so max sig == sig(max x))
        const float mxs = blockReduceMax(sc, red);
        const float mxb = blockReduceMax(bmf, red);
        if (threadIdx.x == 0) {
            rowsig[n * H + h] = mxs;
            rowmax_b[n * H + h] = mxb;
        }
    }
    const float sst = blockReduceSum(st, red);
    const float stt = blockReduceSum(tt, red);
    if (threadIdx.x == 0) {
        const int o = n * 16 + hg;
        part_st[o] = sst;
        part_t[o] = stt;
    }
}

// ---------- kernel B: column-max partials (32-row chunks) ----------
__global__ __launch_bounds__(256) void k_colmax(
    const float* __restrict__ src, const int* __restrict__ bm,
    float* __restrict__ colpart_x, float* __restrict__ colpart_b)
{
    const int chunk = blockIdx.x, n = blockIdx.y, w = threadIdx.x;
    const float* s = src + (size_t)n * HW + chunk * 32 * W + w;
    const int* b = bm + (size_t)n * HW + chunk * 32 * W + w;
    float mx = -3.4e38f, mb = 0.f;
#pragma unroll 8
    for (int r = 0; r < 32; r++) {
        mx = fmaxf(mx, s[r * W]);
        mb = fmaxf(mb, (float)b[r * W]);
    }
    const int o = (n * 8 + chunk) * W + w;
    colpart_x[o] = mx;
    colpart_b[o] = mb;
}

// ---------- kernel C: per-image projection loss ----------
__global__ __launch_bounds__(256) void k_proj(
    const float* __restrict__ colpart_x, const float* __restrict__ colpart_b,
    const float* __restrict__ rowsig, const float* __restrict__ rowmax_b,
    float* __restrict__ proj)
{
    __shared__ float red[4];
    const int n = blockIdx.x, t = threadIdx.x;
    float cx = -3.4e38f, cb = 0.f;
#pragma unroll
    for (int c = 0; c < 8; c++) {
        cx = fmaxf(cx, colpart_x[(n * 8 + c) * W + t]);
        cb = fmaxf(cb, colpart_b[(n * 8 + c) * W + t]);
    }
    const float iy = 1.f / (1.f + expf(-cx));
    const float ty = cb;
    const float ix = rowsig[n * H + t];   // already sigmoid(max x)
    const float tx = rowmax_b[n * H + t];

    const float Sxy = blockReduceSum(ix * tx, red);
    const float Sxx = blockReduceSum(ix * ix, red);
    const float Stx = blockReduceSum(tx * tx, red);
    const float Syw = blockReduceSum(iy * ty, red);
    const float Syy = blockReduceSum(iy * iy, red);
    const float Sty = blockReduceSum(ty * ty, red);
    if (t == 0) {
        const float eps = 0.001f;
        const float lx = 1.f - 2.f * Sxy / (Sxx + Stx + eps);
        const float ly = 1.f - 2.f * Syw / (Syy + Sty + eps);
        proj[n] = lx + ly;
    }
}

// ---------- kernel D: CE + final combine ----------
__global__ __launch_bounds__(256) void k_final(
    const float* __restrict__ logits, const int* __restrict__ tcls,
    const float* __restrict__ ew, const int* __restrict__ num_masks,
    const float* __restrict__ part_st, const float* __restrict__ part_t,
    const float* __restrict__ proj, float* __restrict__ out)
{
    __shared__ float red[4];
    const int t = threadIdx.x;
    float s1 = 0.f, s2 = 0.f;
    for (int i = t; i < NIMG * 16; i += 256) { s1 += part_st[i]; s2 += part_t[i]; }
    const float sum_st = blockReduceSum(s1, red);
    const float sum_t = blockReduceSum(s2, red);
    const float pj = (t < NIMG) ? proj[t] : 0.f;
    const float sum_pj = blockReduceSum(pj, red);

    float wn = 0.f, wsum = 0.f;
    if (t < 200) {
        const float* row = logits + t * 81;
        float mx = -3.4e38f;
        for (int c = 0; c < 81; c++) mx = fmaxf(mx, row[c]);
        float se = 0.f;
        for (int c = 0; c < 81; c++) se += expf(row[c] - mx);
        const float lse = mx + logf(se);
        const int tc = tcls[t];
        const float nll = lse - row[tc];
        const float wv = ew[tc];
        wn = wv * nll;
        wsum = wv;
    }
    const float Swn = blockReduceSum(wn, red);
    const float Sw = blockReduceSum(wsum, red);
    if (t == 0) {
        const float nm = (float)max(num_masks[0], 1);
        const float loss_ce = Swn / Sw;
        const float loss_pw = sum_st / fmaxf(sum_t, 1.f) / nm;
        const float loss_pj = sum_pj / nm;
        out[0] = loss_ce + loss_pw + loss_pj;
    }
}

extern "C" void kernel_launch(void* const* d_in, const int* in_sizes, int n_in,
                              void* d_out, int out_size, void* d_ws, size_t ws_size,
                              hipStream_t stream) {
    const float* pred_logits = (const float*)d_in[0];  // [2,100,81]
    const float* src         = (const float*)d_in[1];  // [64,256,256]
    const float* ew          = (const float*)d_in[2];  // [81]
    const float* ts          = (const float*)d_in[3];  // [64,8,256,256]
    const int*   tcls        = (const int*)d_in[4];    // [2,100]
    const int*   bm          = (const int*)d_in[5];    // [64,256,256]
    const int*   nmasks      = (const int*)d_in[6];    // [1]
    float* out = (float*)d_out;

    float* ws = (float*)d_ws;
    float* part_st   = ws;            // 1024
    float* part_t    = ws + 1024;     // 1024
    float* rowsig    = ws + 2048;     // 16384
    float* rowmax_b  = ws + 18432;    // 16384
    float* colpart_x = ws + 34816;    // 64*8*256 = 131072
    float* colpart_b = ws + 165888;   // 131072
    float* proj      = ws + 296960;   // 64

    k_pairwise<<<dim3(16, NIMG), 256, 0, stream>>>(src, ts, bm, part_st, part_t, rowsig, rowmax_b);
    k_colmax<<<dim3(8, NIMG), 256, 0, stream>>>(src, bm, colpart_x, colpart_b);
    k_proj<<<NIMG, 256, 0, stream>>>(colpart_x, colpart_b, rowsig, rowmax_b, proj);
    k_final<<<1, 256, 0, stream>>>(pred_logits, tcls, ew, nmasks, part_st, part_t, proj, out);
}